// Round 6
// baseline (403.642 us; speedup 1.0000x reference)
//
#include <hip/hip_runtime.h>
#include <math.h>

#define D_MODEL 512
#define BATCH 8
#define SEQ 512
#define HEAD 64
#define DK 4
#define DV 8
#define HIDD 10

// proj tiled-GEMM params: 8x8 register tile -> 64 FMA per 4 ds_read_b128
#define MR 64    // rows per block
#define KC 32    // k-chunk (40 KB LDS)
#define NC 256   // cols per block

// ---------------------------------------------------------------------------
// Projection as tiled GEMM: [4096 x 512] @ [512 x 1024] -> {Q2|K2|V2},
// head-major outputs: Q2/K2 = [b][h][s][4], V2 = [b][h][s][8].
// 256 threads = 32 col-threads (8 cols each) x 8 row-threads (8 rows each).
// Per k: 2 b128 W + 2 b128 x feed 64 FMA (2x better LDS ratio than R5).
// ---------------------------------------------------------------------------
__global__ __launch_bounds__(256) void proj_kernel(
    const float* __restrict__ xq, const float* __restrict__ xkv,
    const float* __restrict__ Wq, const float* __restrict__ Wk,
    const float* __restrict__ Wv,
    float* __restrict__ Q2, float* __restrict__ K2, float* __restrict__ V2)
{
    __shared__ float xt[KC * MR];   // [k][r]  8 KB
    __shared__ float wt[KC * NC];   // [k][c] 32 KB

    const int t  = threadIdx.x;
    const int bj = blockIdx.x & 3;
    const int br = blockIdx.x >> 2;
    const int r0 = br * MR;

    const float* X; const float* W; int ldw; int c0;
    if (bj == 0)      { X = xq;  W = Wq; ldw = 256; c0 = 0;   }
    else if (bj == 1) { X = xkv; W = Wk; ldw = 256; c0 = 0;   }
    else if (bj == 2) { X = xkv; W = Wv; ldw = 512; c0 = 0;   }
    else              { X = xkv; W = Wv; ldw = 512; c0 = 256; }

    const int ct = t & 31;          // col-thread: cols ct*8 .. ct*8+7
    const int rt = t >> 5;          // row-thread: rows rt*8 .. rt*8+7
    const int rs = t & 63;          // x-staging row
    const int kx = t >> 6;          // x-staging k-octet 0..3
    const int rg = t >> 6;          // w-staging wave id
    const int cq = t & 63;          // w-staging col quad

    float acc[8][8];
#pragma unroll
    for (int r = 0; r < 8; ++r)
#pragma unroll
        for (int c = 0; c < 8; ++c) acc[r][c] = 0.f;

    for (int kc = 0; kc < D_MODEL; kc += KC) {
        // ---- stage x tile transposed [k][r] (2-way bank groups = free) ----
        {
            const float4 xa = *(const float4*)(X + (long)(r0 + rs) * D_MODEL + kc + kx * 8);
            const float4 xb = *(const float4*)(X + (long)(r0 + rs) * D_MODEL + kc + kx * 8 + 4);
            xt[(kx * 8 + 0) * MR + rs] = xa.x;
            xt[(kx * 8 + 1) * MR + rs] = xa.y;
            xt[(kx * 8 + 2) * MR + rs] = xa.z;
            xt[(kx * 8 + 3) * MR + rs] = xa.w;
            xt[(kx * 8 + 4) * MR + rs] = xb.x;
            xt[(kx * 8 + 5) * MR + rs] = xb.y;
            xt[(kx * 8 + 6) * MR + rs] = xb.z;
            xt[(kx * 8 + 7) * MR + rs] = xb.w;
        }
        // ---- stage W tile: wave rg loads rows i*4+rg, 1 KB contiguous ----
#pragma unroll
        for (int i = 0; i < 8; ++i) {
            const int row = i * 4 + rg;
            *(float4*)(wt + row * NC + cq * 4) =
                *(const float4*)(W + (long)(kc + row) * ldw + c0 + cq * 4);
        }
        __syncthreads();

        // ---- compute: 8x8 register block, 64 FMA per k, 4 b128 reads ----
#pragma unroll 2
        for (int k = 0; k < KC; ++k) {
            const float4 w0 = *(const float4*)(wt + k * NC + ct * 8);
            const float4 w1 = *(const float4*)(wt + k * NC + ct * 8 + 4);
            const float4 x0 = *(const float4*)(xt + k * MR + rt * 8);
            const float4 x1 = *(const float4*)(xt + k * MR + rt * 8 + 4);
            const float xr[8] = {x0.x, x0.y, x0.z, x0.w, x1.x, x1.y, x1.z, x1.w};
            const float wc[8] = {w0.x, w0.y, w0.z, w0.w, w1.x, w1.y, w1.z, w1.w};
#pragma unroll
            for (int r = 0; r < 8; ++r)
#pragma unroll
                for (int c = 0; c < 8; ++c)
                    acc[r][c] = fmaf(xr[r], wc[c], acc[r][c]);
        }
        __syncthreads();
    }

    // ---- epilogue: head-major scatter ----
    const int b  = r0 >> 9;
    const int sb = (r0 & 511) + rt * 8;
    if (bj <= 1) {
        // cols ct*8..ct*8+7 = heads 2*ct, 2*ct+1 (dk=4 each)
        float* dst = (bj == 0) ? Q2 : K2;
        const long h0 = (long)b * HEAD + ct * 2;
#pragma unroll
        for (int r = 0; r < 8; ++r) {
            *(float4*)(dst + (h0 * SEQ + sb + r) * 4) =
                make_float4(acc[r][0], acc[r][1], acc[r][2], acc[r][3]);
            *(float4*)(dst + ((h0 + 1) * SEQ + sb + r) * 4) =
                make_float4(acc[r][4], acc[r][5], acc[r][6], acc[r][7]);
        }
    } else {
        // cols c0+ct*8..+7 = one full head (dv=8)
        const int h = (c0 >> 3) + ct;
        const long vb = ((long)b * HEAD + h) * SEQ;
#pragma unroll
        for (int r = 0; r < 8; ++r) {
            *(float4*)(V2 + (vb + sb + r) * 8) =
                make_float4(acc[r][0], acc[r][1], acc[r][2], acc[r][3]);
            *(float4*)(V2 + (vb + sb + r) * 8 + 4) =
                make_float4(acc[r][4], acc[r][5], acc[r][6], acc[r][7]);
        }
    }
}

// ---------------------------------------------------------------------------
// Attention: one block per (b,h); 256 threads; 2 queries/thread (q=2t, 2t+1)
// so each K/V LDS read feeds both queries (halves LDS traffic vs R5).
// Online softmax. Causal quirk: masked (s>q) scores are exactly 0 and
// participate; in-loop s=q0+1 is predicated to 0 for q0; s>q1 handled as
// lump exp(-M)*(count, suffixSumV) shared by both queries.
// ---------------------------------------------------------------------------
template <int CAUSAL>
__global__ __launch_bounds__(256) void attn_kernel(
    const float* __restrict__ Q2, const float* __restrict__ K2,
    const float* __restrict__ V2, float* __restrict__ O)
{
    extern __shared__ float smem[];
    float* Kl = smem;                 // SEQ*DK = 2048 floats
    float* Vl = smem + SEQ * DK;      // SEQ*DV = 4096 floats
    float* cs = Vl + SEQ * DV;        // 33*DV  =  264 floats (causal only)

    const int t = threadIdx.x;
    const int bh = blockIdx.x;        // b*64 + h
    const int b = bh >> 6;
    const int h = bh & 63;

    const float4* Ks = (const float4*)(K2 + (long)bh * SEQ * DK);
    ((float4*)Kl)[t]       = Ks[t];
    ((float4*)Kl)[t + 256] = Ks[t + 256];
    const float4* Vs = (const float4*)(V2 + (long)bh * SEQ * DV);
#pragma unroll
    for (int i = 0; i < 4; ++i)
        ((float4*)Vl)[t + i * 256] = Vs[t + i * 256];
    __syncthreads();

    if (CAUSAL) {
        const int ch = t >> 3, d = t & 7;
        float s16 = 0.f;
#pragma unroll
        for (int i = 0; i < 16; ++i) s16 += Vl[(ch * 16 + i) * 8 + d];
        cs[ch * 8 + d] = s16;
        __syncthreads();
        if (t < 8) {
            cs[256 + t] = 0.f;
            float run = 0.f;
            for (int c2 = 31; c2 >= 0; --c2) {
                run += cs[c2 * 8 + t];
                cs[c2 * 8 + t] = run;
            }
        }
        __syncthreads();
    }

    const int q0 = 2 * t, q1 = 2 * t + 1;
    const float4 qa = *(const float4*)(Q2 + ((long)bh * SEQ + q0) * 4);
    const float4 qb = *(const float4*)(Q2 + ((long)bh * SEQ + q1) * 4);
    const float qa0 = qa.x*0.5f, qa1 = qa.y*0.5f, qa2 = qa.z*0.5f, qa3 = qa.w*0.5f;
    const float qb0 = qb.x*0.5f, qb1 = qb.y*0.5f, qb2 = qb.z*0.5f, qb3 = qb.w*0.5f;

    const int bound = CAUSAL ? q1 : (SEQ - 1);

    float m0 = -INFINITY, l0 = 0.f, m1 = -INFINITY, l1 = 0.f;
    float A0[8], A1[8];
#pragma unroll
    for (int d = 0; d < 8; ++d) { A0[d] = 0.f; A1[d] = 0.f; }

    int s0 = 0;
    for (; s0 + 8 <= bound + 1; s0 += 8) {
        float sa[8], sb[8];
#pragma unroll
        for (int i = 0; i < 8; ++i) {
            const float4 k4 = *(const float4*)(Kl + (s0 + i) * 4);
            sa[i] = fmaf(qa0, k4.x, fmaf(qa1, k4.y, fmaf(qa2, k4.z, qa3 * k4.w)));
            sb[i] = fmaf(qb0, k4.x, fmaf(qb1, k4.y, fmaf(qb2, k4.z, qb3 * k4.w)));
            if (CAUSAL) sa[i] = (s0 + i <= q0) ? sa[i] : 0.f;  // mult-mask quirk
        }
        float ga = fmaxf(fmaxf(fmaxf(sa[0], sa[1]), fmaxf(sa[2], sa[3])),
                         fmaxf(fmaxf(sa[4], sa[5]), fmaxf(sa[6], sa[7])));
        float gb = fmaxf(fmaxf(fmaxf(sb[0], sb[1]), fmaxf(sb[2], sb[3])),
                         fmaxf(fmaxf(sb[4], sb[5]), fmaxf(sb[6], sb[7])));
        if (ga > m0) {
            float sc = __expf(m0 - ga);
            l0 *= sc;
#pragma unroll
            for (int d = 0; d < 8; ++d) A0[d] *= sc;
            m0 = ga;
        }
        if (gb > m1) {
            float sc = __expf(m1 - gb);
            l1 *= sc;
#pragma unroll
            for (int d = 0; d < 8; ++d) A1[d] *= sc;
            m1 = gb;
        }
#pragma unroll
        for (int i = 0; i < 8; ++i) {
            float p0 = __expf(sa[i] - m0);
            float p1 = __expf(sb[i] - m1);
            l0 += p0; l1 += p1;
            const float4 v0 = *(const float4*)(Vl + (s0 + i) * 8);
            const float4 v1 = *(const float4*)(Vl + (s0 + i) * 8 + 4);
            A0[0] = fmaf(p0, v0.x, A0[0]); A0[1] = fmaf(p0, v0.y, A0[1]);
            A0[2] = fmaf(p0, v0.z, A0[2]); A0[3] = fmaf(p0, v0.w, A0[3]);
            A0[4] = fmaf(p0, v1.x, A0[4]); A0[5] = fmaf(p0, v1.y, A0[5]);
            A0[6] = fmaf(p0, v1.z, A0[6]); A0[7] = fmaf(p0, v1.w, A0[7]);
            A1[0] = fmaf(p1, v0.x, A1[0]); A1[1] = fmaf(p1, v0.y, A1[1]);
            A1[2] = fmaf(p1, v0.z, A1[2]); A1[3] = fmaf(p1, v0.w, A1[3]);
            A1[4] = fmaf(p1, v1.x, A1[4]); A1[5] = fmaf(p1, v1.y, A1[5]);
            A1[6] = fmaf(p1, v1.z, A1[6]); A1[7] = fmaf(p1, v1.w, A1[7]);
        }
    }
    for (int s = s0; s <= bound; ++s) {   // tail (<8 per lane)
        const float4 k4 = *(const float4*)(Kl + s * 4);
        float sa = fmaf(qa0, k4.x, fmaf(qa1, k4.y, fmaf(qa2, k4.z, qa3 * k4.w)));
        float sb = fmaf(qb0, k4.x, fmaf(qb1, k4.y, fmaf(qb2, k4.z, qb3 * k4.w)));
        if (CAUSAL) sa = (s <= q0) ? sa : 0.f;
        if (sa > m0) {
            float sc = __expf(m0 - sa);
            l0 *= sc;
#pragma unroll
            for (int d = 0; d < 8; ++d) A0[d] *= sc;
            m0 = sa;
        }
        if (sb > m1) {
            float sc = __expf(m1 - sb);
            l1 *= sc;
#pragma unroll
            for (int d = 0; d < 8; ++d) A1[d] *= sc;
            m1 = sb;
        }
        float p0 = __expf(sa - m0);
        float p1 = __expf(sb - m1);
        l0 += p0; l1 += p1;
        const float4 v0 = *(const float4*)(Vl + s * 8);
        const float4 v1 = *(const float4*)(Vl + s * 8 + 4);
        A0[0] = fmaf(p0, v0.x, A0[0]); A0[1] = fmaf(p0, v0.y, A0[1]);
        A0[2] = fmaf(p0, v0.z, A0[2]); A0[3] = fmaf(p0, v0.w, A0[3]);
        A0[4] = fmaf(p0, v1.x, A0[4]); A0[5] = fmaf(p0, v1.y, A0[5]);
        A0[6] = fmaf(p0, v1.z, A0[6]); A0[7] = fmaf(p0, v1.w, A0[7]);
        A1[0] = fmaf(p1, v0.x, A1[0]); A1[1] = fmaf(p1, v0.y, A1[1]);
        A1[2] = fmaf(p1, v0.z, A1[2]); A1[3] = fmaf(p1, v0.w, A1[3]);
        A1[4] = fmaf(p1, v1.x, A1[4]); A1[5] = fmaf(p1, v1.y, A1[5]);
        A1[6] = fmaf(p1, v1.z, A1[6]); A1[7] = fmaf(p1, v1.w, A1[7]);
    }

    if (CAUSAL && t < 255) {
        // lump for s in (q1, SEQ): shared suffix sum + count for both queries.
        // m0 already >= 0 (saw the in-loop zero); m1 may need the 0 clamp.
        const int n = SEQ - 1 - q1;
        const int nq = q1 + 1;
        const int cq2 = nq >> 4;
        float sv[8];
#pragma unroll
        for (int d = 0; d < 8; ++d) sv[d] = cs[(cq2 + 1) * 8 + d];
        for (int s = nq; s < (cq2 + 1) * 16; ++s) {
            const float4 v0 = *(const float4*)(Vl + s * 8);
            const float4 v1 = *(const float4*)(Vl + s * 8 + 4);
            sv[0]+=v0.x; sv[1]+=v0.y; sv[2]+=v0.z; sv[3]+=v0.w;
            sv[4]+=v1.x; sv[5]+=v1.y; sv[6]+=v1.z; sv[7]+=v1.w;
        }
        float pm0 = __expf(-m0);
        l0 += pm0 * (float)n;
#pragma unroll
        for (int d = 0; d < 8; ++d) A0[d] = fmaf(pm0, sv[d], A0[d]);

        float M1 = fmaxf(m1, 0.f);
        float sc1 = __expf(m1 - M1);
        float pm1 = __expf(-M1);
        l1 = l1 * sc1 + pm1 * (float)n;
#pragma unroll
        for (int d = 0; d < 8; ++d) A1[d] = A1[d] * sc1 + pm1 * sv[d];
    }

    const float i0 = 1.0f / l0, i1 = 1.0f / l1;
    const long ob0 = ((long)b * SEQ + q0) * 512 + h * DV;
    const long ob1 = ((long)b * SEQ + q1) * 512 + h * DV;
    *(float4*)(O + ob0)     = make_float4(A0[0]*i0, A0[1]*i0, A0[2]*i0, A0[3]*i0);
    *(float4*)(O + ob0 + 4) = make_float4(A0[4]*i0, A0[5]*i0, A0[6]*i0, A0[7]*i0);
    *(float4*)(O + ob1)     = make_float4(A1[0]*i1, A1[1]*i1, A1[2]*i1, A1[3]*i1);
    *(float4*)(O + ob1 + 4) = make_float4(A1[4]*i1, A1[5]*i1, A1[6]*i1, A1[7]*i1);
}

// ---------------------------------------------------------------------------
// Fused residual + LayerNorm + MLP (512 -> 10 -> 512).
// One WAVE per row; 256 threads = 4 rows/block. (unchanged)
// ---------------------------------------------------------------------------
__global__ __launch_bounds__(256) void ln_mlp_kernel(
    const float* __restrict__ x, const float* __restrict__ fx,
    const float* __restrict__ g, const float* __restrict__ beta,
    const float* __restrict__ w1, const float* __restrict__ b1,
    const float* __restrict__ w2, const float* __restrict__ b2,
    float* __restrict__ out)
{
    const int t = threadIdx.x;
    const int lane = t & 63;
    const int row = blockIdx.x * 4 + (t >> 6);
    const long base = (long)row * D_MODEL;
    const int e0 = lane * 8;

    const float4 xa = *(const float4*)(x + base + e0);
    const float4 xb = *(const float4*)(x + base + e0 + 4);
    const float4 fa = *(const float4*)(fx + base + e0);
    const float4 fb = *(const float4*)(fx + base + e0 + 4);
    float z[8] = {xa.x+fa.x, xa.y+fa.y, xa.z+fa.z, xa.w+fa.w,
                  xb.x+fb.x, xb.y+fb.y, xb.z+fb.z, xb.w+fb.w};

    float sum = 0.f;
#pragma unroll
    for (int j = 0; j < 8; ++j) sum += z[j];
#pragma unroll
    for (int o = 32; o > 0; o >>= 1) sum += __shfl_xor(sum, o);
    float mu = sum * (1.0f / 512.0f);

    float d[8], ss = 0.f;
#pragma unroll
    for (int j = 0; j < 8; ++j) { d[j] = z[j] - mu; ss += d[j] * d[j]; }
#pragma unroll
    for (int o = 32; o > 0; o >>= 1) ss += __shfl_xor(ss, o);
    float rs = rsqrtf(ss * (1.0f / 512.0f) + 1e-5f);

    const float4 ga = *(const float4*)(g + e0);
    const float4 gb = *(const float4*)(g + e0 + 4);
    const float4 ba = *(const float4*)(beta + e0);
    const float4 bb = *(const float4*)(beta + e0 + 4);
    const float gg[8] = {ga.x,ga.y,ga.z,ga.w,gb.x,gb.y,gb.z,gb.w};
    const float bt[8] = {ba.x,ba.y,ba.z,ba.w,bb.x,bb.y,bb.z,bb.w};
    float y[8];
#pragma unroll
    for (int j = 0; j < 8; ++j) y[j] = d[j] * rs * gg[j] + bt[j];

    float part[HIDD];
#pragma unroll
    for (int i = 0; i < HIDD; ++i) {
        const float4 wa = *(const float4*)(w1 + i * 512 + e0);
        const float4 wb = *(const float4*)(w1 + i * 512 + e0 + 4);
        part[i] = y[0]*wa.x + y[1]*wa.y + y[2]*wa.z + y[3]*wa.w
                + y[4]*wb.x + y[5]*wb.y + y[6]*wb.z + y[7]*wb.w;
    }
#pragma unroll
    for (int i = 0; i < HIDD; ++i)
#pragma unroll
        for (int o = 32; o > 0; o >>= 1) part[i] += __shfl_xor(part[i], o);

    float hv[HIDD];
#pragma unroll
    for (int i = 0; i < HIDD; ++i) hv[i] = fmaxf(part[i] + b1[i], 0.f);

    float o8[8];
#pragma unroll
    for (int j = 0; j < 8; ++j) o8[j] = b2[e0 + j];
#pragma unroll
    for (int i = 0; i < HIDD; ++i)
#pragma unroll
        for (int j = 0; j < 8; ++j)
            o8[j] = fmaf(hv[i], w2[(long)(e0 + j) * 10 + i], o8[j]);

    *(float4*)(out + base + e0)     = make_float4(o8[0], o8[1], o8[2], o8[3]);
    *(float4*)(out + base + e0 + 4) = make_float4(o8[4], o8[5], o8[6], o8[7]);
}

extern "C" void kernel_launch(void* const* d_in, const int* in_sizes, int n_in,
                              void* d_out, int out_size, void* d_ws, size_t ws_size,
                              hipStream_t stream) {
    (void)in_sizes; (void)n_in; (void)out_size; (void)ws_size;
    const float* x    = (const float*)d_in[0];
    const float* xenc = (const float*)d_in[1];
    const float* Wq   = (const float*)d_in[2];
    const float* Wk   = (const float*)d_in[3];
    const float* Wv   = (const float*)d_in[4];
    const float* ln_g = (const float*)d_in[5];
    const float* ln_b = (const float*)d_in[6];
    const float* w1   = (const float*)d_in[7];
    const float* b1   = (const float*)d_in[8];
    const float* w2   = (const float*)d_in[9];
    const float* b2   = (const float*)d_in[10];
    float* out = (float*)d_out;

    float* ws = (float*)d_ws;
    float* Q2 = ws;                   // [b][h][s][4]
    float* K2 = Q2 + 1048576;         // [b][h][s][4]
    float* V2 = K2 + 1048576;         // [b][h][s][8]
    float* A  = V2 + 2097152;         // row-major [b][s][512]

    const int nrows = BATCH * SEQ;    // 4096
    const size_t lds_cross  = (size_t)(SEQ * DK + SEQ * DV) * 4;          // 24576
    const size_t lds_causal = lds_cross + (size_t)(33 * DV) * 4;          // 25632
    const int proj_grid = (nrows / MR) * 4;                               // 256

    // Stage 1: self-attention (causal multiplicative mask)
    proj_kernel<<<dim3(proj_grid), 256, 0, stream>>>(x, x, Wq, Wk, Wv, Q2, K2, V2);
    attn_kernel<1><<<dim3(BATCH * HEAD), 256, lds_causal, stream>>>(Q2, K2, V2, A);

    // Stage 2: cross-attention (same weights — faithful quirk)
    proj_kernel<<<dim3(proj_grid), 256, 0, stream>>>(A, xenc, Wq, Wk, Wv, Q2, K2, V2);
    attn_kernel<0><<<dim3(BATCH * HEAD), 256, lds_cross, stream>>>(Q2, K2, V2, A);

    // Stage 3: residual(x) + LayerNorm + MLP
    ln_mlp_kernel<<<dim3(nrows / 4), 256, 0, stream>>>(x, A, ln_g, ln_b,
                                                       w1, b1, w2, b2, out);
}